// Round 10
// baseline (66.246 us; speedup 1.0000x reference)
//
#include <hip/hip_runtime.h>

#define NPIX 9216
#define PLANE 82944           // 288*288
#define WPL 230400            // floats per (o,i) weight plane = 9216*25

typedef float f4v __attribute__((ext_vector_type(4)));

__global__ __launch_bounds__(192)
void lfk10(const float* __restrict__ lf, const float* __restrict__ wts,
           const float* __restrict__ bias, float* __restrict__ out)
{
    __shared__ float red[2][64][9];       // partials from waves 1,2 (4.6 KB)

    const int tid  = threadIdx.x;
    const int wv   = tid >> 6;            // i-split wave 0..2
    const int lane = tid & 63;
    const int px   = lane & 15;
    const int b    = lane >> 4;
    const int bid  = blockIdx.x;
    const int swz  = (bid & 7) * 216 + (bid >> 3);   // bijective XCD swizzle
    const int tile = swz / 3;
    const int og   = swz - tile * 3;
    const int oh   = tile / 6;
    const int tc   = tile - oh * 6;
    const int g    = tile * 16 + px;
    const int ow   = tc * 16 + px;
    const int y0   = oh * 3 - 2;          // pt = pl = 2, no bottom/right pad
    const int x0   = ow * 3 - 2;
    const int xcl  = (x0 < 0) ? 0 : x0;
    const bool xneg = (x0 < 0);           // only px==0 in tc==0 blocks
    const bool tc0  = (tc == 0);          // block-uniform
    const bool oh0  = (oh == 0);          // block-uniform

    float acc[3][3] = {{0.f,0.f,0.f},{0.f,0.f,0.f},{0.f,0.f,0.f}};

    f4v  Pv[3][5];
    float Pe[3][5];

    #define LW(oc, r0,r1,r2,r3,r4,r5,r24) do {                     \
        const float* _p = wbase + (oc) * (9 * WPL);                \
        __builtin_memcpy(&r0, _p,      16);                        \
        __builtin_memcpy(&r1, _p + 4,  16);                        \
        __builtin_memcpy(&r2, _p + 8,  16);                        \
        __builtin_memcpy(&r3, _p + 12, 16);                        \
        __builtin_memcpy(&r4, _p + 16, 16);                        \
        __builtin_memcpy(&r5, _p + 20, 16);                        \
        r24 = _p[24];                                              \
    } while (0)

    #define DOFMA(oc, r0,r1,r2,r3,r4,r5,r24) do {                  \
        float wk[25];                                              \
        wk[0]=r0.x; wk[1]=r0.y; wk[2]=r0.z; wk[3]=r0.w;            \
        wk[4]=r1.x; wk[5]=r1.y; wk[6]=r1.z; wk[7]=r1.w;            \
        wk[8]=r2.x; wk[9]=r2.y; wk[10]=r2.z; wk[11]=r2.w;          \
        wk[12]=r3.x; wk[13]=r3.y; wk[14]=r3.z; wk[15]=r3.w;        \
        wk[16]=r4.x; wk[17]=r4.y; wk[18]=r4.z; wk[19]=r4.w;        \
        wk[20]=r5.x; wk[21]=r5.y; wk[22]=r5.z; wk[23]=r5.w;        \
        wk[24]=r24;                                                \
        _Pragma("unroll")                                          \
        for (int c = 0; c < 3; ++c) {                              \
            _Pragma("unroll")                                      \
            for (int kh = 0; kh < 5; ++kh) {                       \
                const f4v A = Pv[c][kh];                           \
                const float e = Pe[c][kh];                         \
                float q0,q1,q2,q3,q4;                              \
                if (tc0) {                                         \
                    q0 = xneg ? 0.f : A.x;                         \
                    q1 = xneg ? 0.f : A.y;                         \
                    q2 = xneg ? A.x : A.z;                         \
                    q3 = xneg ? A.y : A.w;                         \
                    q4 = xneg ? A.z : e;                           \
                } else {                                           \
                    q0=A.x; q1=A.y; q2=A.z; q3=A.w; q4=e;          \
                }                                                  \
                acc[oc][c] = fmaf(wk[kh*5+0], q0, acc[oc][c]);     \
                acc[oc][c] = fmaf(wk[kh*5+1], q1, acc[oc][c]);     \
                acc[oc][c] = fmaf(wk[kh*5+2], q2, acc[oc][c]);     \
                acc[oc][c] = fmaf(wk[kh*5+3], q3, acc[oc][c]);     \
                acc[oc][c] = fmaf(wk[kh*5+4], q4, acc[oc][c]);     \
            }                                                      \
        }                                                          \
    } while (0)

    const int i0 = wv * 3;
    #pragma unroll 1
    for (int s = 0; s < 3; ++s) {
        const int i = i0 + s;

        // ---- patches: 3c x 5 rows, dwordx4 + dword, direct global->reg ----
        #pragma unroll
        for (int c = 0; c < 3; ++c) {
            const float* rb = lf + ((b * 9 + i) * 3 + c) * PLANE + xcl;
            #pragma unroll
            for (int kh = 0; kh < 5; ++kh) {
                const int y = y0 + kh;
                if (!oh0 || y >= 0) {          // block-uniform
                    const float* rp = rb + y * 288;
                    f4v A; __builtin_memcpy(&A, rp, 16);
                    Pv[c][kh] = A;
                    Pe[c][kh] = rp[4];         // x0+4 <= 287: in-bounds
                } else {
                    Pv[c][kh] = (f4v)0.f;
                    Pe[c][kh] = 0.f;
                }
            }
        }

        // ---- weights direct global->reg, 2-deep o-pipeline ----
        const float* wbase = wts + (size_t)((og * 3) * 9 + i) * WPL + g * 25;
        f4v a0,a1,a2,a3,a4,a5; float a24;
        f4v b0,b1,b2,b3,b4,b5; float b24;
        LW(0, a0,a1,a2,a3,a4,a5,a24);
        LW(1, b0,b1,b2,b3,b4,b5,b24);
        DOFMA(0, a0,a1,a2,a3,a4,a5,a24);
        LW(2, a0,a1,a2,a3,a4,a5,a24);
        DOFMA(1, b0,b1,b2,b3,b4,b5,b24);
        DOFMA(2, a0,a1,a2,a3,a4,a5,a24);
    }

    // ---- cross-wave partial reduction (one barrier total) ----
    if (wv != 0) {
        #pragma unroll
        for (int oc = 0; oc < 3; ++oc)
            #pragma unroll
            for (int c = 0; c < 3; ++c)
                red[wv - 1][lane][oc * 3 + c] = acc[oc][c];
    }
    __syncthreads();

    if (wv == 0) {
        #pragma unroll
        for (int oc = 0; oc < 3; ++oc) {
            #pragma unroll
            for (int c = 0; c < 3; ++c)
                acc[oc][c] += red[0][lane][oc * 3 + c] + red[1][lane][oc * 3 + c];
            const int o = og * 3 + oc;
            const float bo = bias[o * NPIX + g];
            #pragma unroll
            for (int c = 0; c < 3; ++c) {
                float v = acc[oc][c] + bo;
                v = fminf(fmaxf(v, 0.f), 1.f);
                out[((b * 9 + o) * 3 + c) * NPIX + g] = v;
            }
        }
    }
    #undef LW
    #undef DOFMA
}

extern "C" void kernel_launch(void* const* d_in, const int* in_sizes, int n_in,
                              void* d_out, int out_size, void* d_ws, size_t ws_size,
                              hipStream_t stream) {
    const float* lf   = (const float*)d_in[0];
    const float* wts  = (const float*)d_in[1];
    const float* bias = (const float*)d_in[2];
    float* out = (float*)d_out;
    (void)d_ws; (void)ws_size; (void)in_sizes; (void)n_in; (void)out_size;

    dim3 grid(576 * 3);     // 1728 blocks x 3 waves (i-split) = 5184 waves
    dim3 block(192);
    lfk10<<<grid, block, 0, stream>>>(lf, wts, bias, out);
}